// Round 1
// 32387.930 us; speedup vs baseline: 1.1018x; 1.1018x over previous
//
#include <hip/hip_runtime.h>

// Problem constants
#define BB   32      // batch
#define TT_  512     // sequence length
#define DD   1024    // input dim
#define HH   1024    // hidden
#define RR_  64      // low-rank
#define FH   4096    // 4*H
#define TC   32      // timestep chunk (keeps workspace ~21 MB)

typedef __attribute__((ext_vector_type(8))) short          bf16x8;   // MFMA A/B frag (8 bf16)
typedef __attribute__((ext_vector_type(4))) float          f32x4;    // MFMA C/D frag
typedef __attribute__((ext_vector_type(4))) unsigned short us4;

// fp32 -> bf16 bits, round-to-nearest-even (pure integer: no hip_bf16 type games)
__device__ __forceinline__ unsigned short f2bf(float x) {
    union { float f; unsigned u; } v; v.f = x;
    return (unsigned short)((v.u + 0x7FFFu + ((v.u >> 16) & 1u)) >> 16);
}

// ---------------------------------------------------------------------------
// Zero-init kernel for state buffers (ws is poisoned 0xAA before every call)
// ---------------------------------------------------------------------------
__global__ void init_zero(float4* p, int n4) {
    int i = blockIdx.x * blockDim.x + threadIdx.x;
    if (i < n4) p[i] = make_float4(0.f, 0.f, 0.f, 0.f);
}

// ---------------------------------------------------------------------------
// bf16-MFMA GEMM: C[m][n] = sum_k Arow(m)[k] * W[n][k] (+ bias[n]), fp32 I/O.
// Row m decomposes as m = tt*32 + b ; rowptr = Abase + (m>>5)*strideT + (m&31)*strideB
// fp32 inputs converted to bf16 (RNE) at LDS-staging time; fp32 accumulate.
// 256 threads = 4 waves in 2x2; each wave owns (BM/2)x(BN/2) via 16x16x32 MFMA.
// BK=32. Register prefetch (1 deep) hides L2 latency under MFMA of prev tile.
// Fragment layout (m89-verified): A/B frag = 8 contiguous K elems, row=lane&15,
// kgroup=lane>>4. C/D: col=lane&15 (N), row=(lane>>4)*4+reg (M).
// ---------------------------------------------------------------------------
template<int BM, int BN>
__global__ __launch_bounds__(256) void gemm_mfma(
    const float* __restrict__ Abase, long strideT, long strideB,
    const float* __restrict__ W, const float* __restrict__ bias,
    float* __restrict__ C, int M, int N, int K)
{
    constexpr int BK  = 32;
    constexpr int WTM = BM / 2, WTN = BN / 2;      // per-wave output tile
    constexpr int MI  = WTM / 16, NI = WTN / 16;   // 16x16 frags per wave
    constexpr int AU  = BM * (BK / 4) / 256;       // float4 staging units/thread
    constexpr int BU  = BN * (BK / 4) / 256;
    static_assert(BM * (BK / 4) % 256 == 0 && BN * (BK / 4) % 256 == 0, "staging");

    __shared__ __align__(16) unsigned short As[BM * BK];  // bf16 tile, 64B rows
    __shared__ __align__(16) unsigned short Bs[BN * BK];

    const int tid  = threadIdx.x;
    const int lane = tid & 63, wave = tid >> 6;
    const int wm   = wave >> 1, wn = wave & 1;     // 2x2 wave grid
    const int kg   = lane >> 4;                    // k-group 0..3
    const int lr   = lane & 15;
    const long bm  = (long)blockIdx.y * BM;
    const long bn  = (long)blockIdx.x * BN;

    // Per-thread staging source pointers (strided row map folded in once).
    const float* ag[AU]; int alds[AU];
    const float* bg[BU]; int blds[BU];
#pragma unroll
    for (int i = 0; i < AU; ++i) {
        int u = i * 256 + tid, row = u >> 3, uc = u & 7;   // 8 x 16B units per row
        long m = bm + row;
        ag[i]   = Abase + (m >> 5) * strideT + (m & 31) * strideB + uc * 4;
        alds[i] = row * BK + uc * 4;
    }
#pragma unroll
    for (int i = 0; i < BU; ++i) {
        int u = i * 256 + tid, row = u >> 3, uc = u & 7;
        bg[i]   = W + (long)(bn + row) * K + uc * 4;
        blds[i] = row * BK + uc * 4;
    }

    f32x4 acc[MI][NI] = {};

    // prefetch k0 = 0
    float4 av[AU], bv[BU];
#pragma unroll
    for (int i = 0; i < AU; ++i) av[i] = *(const float4*)(ag[i]);
#pragma unroll
    for (int i = 0; i < BU; ++i) bv[i] = *(const float4*)(bg[i]);

    for (int k0 = 0; k0 < K; k0 += BK) {
        __syncthreads();                 // previous tile's readers done
#pragma unroll
        for (int i = 0; i < AU; ++i) {
            us4 t; t.x = f2bf(av[i].x); t.y = f2bf(av[i].y);
                   t.z = f2bf(av[i].z); t.w = f2bf(av[i].w);
            *(us4*)&As[alds[i]] = t;
        }
#pragma unroll
        for (int i = 0; i < BU; ++i) {
            us4 t; t.x = f2bf(bv[i].x); t.y = f2bf(bv[i].y);
                   t.z = f2bf(bv[i].z); t.w = f2bf(bv[i].w);
            *(us4*)&Bs[blds[i]] = t;
        }
        __syncthreads();                 // tile visible

        if (k0 + BK < K) {               // prefetch next tile under compute
#pragma unroll
            for (int i = 0; i < AU; ++i) av[i] = *(const float4*)(ag[i] + k0 + BK);
#pragma unroll
            for (int i = 0; i < BU; ++i) bv[i] = *(const float4*)(bg[i] + k0 + BK);
        }

        bf16x8 af[MI], bfr[NI];
#pragma unroll
        for (int mi = 0; mi < MI; ++mi)
            af[mi] = *(const bf16x8*)&As[(wm * WTM + mi * 16 + lr) * BK + kg * 8];
#pragma unroll
        for (int ni = 0; ni < NI; ++ni)
            bfr[ni] = *(const bf16x8*)&Bs[(wn * WTN + ni * 16 + lr) * BK + kg * 8];
#pragma unroll
        for (int mi = 0; mi < MI; ++mi)
#pragma unroll
            for (int ni = 0; ni < NI; ++ni)
                acc[mi][ni] = __builtin_amdgcn_mfma_f32_16x16x32_bf16(
                    af[mi], bfr[ni], acc[mi][ni], 0, 0, 0);
    }

    // Epilogue: C/D layout col=lane&15 (N), row=(lane>>4)*4+reg (M).
    const int rbase = (lane >> 4) * 4;
#pragma unroll
    for (int mi = 0; mi < MI; ++mi) {
        long m = bm + wm * WTM + mi * 16 + rbase;
#pragma unroll
        for (int ni = 0; ni < NI; ++ni) {
            long n = bn + wn * WTN + ni * 16 + lr;
            float bia = bias ? bias[n] : 0.f;
#pragma unroll
            for (int r = 0; r < 4; ++r)
                C[(m + r) * (long)N + n] = acc[mi][ni][r] + bia;
        }
    }
}

// ---------------------------------------------------------------------------
// sLSTM scan step. Grid: 256 blocks x 256 threads. Block owns 4 j-columns
// (16 U-rows over 4 gates) x all 32 batches. h kept in transposed fp32
// layout: float4 index d4*32+b holds h[b][4*d4..+3].
// ---------------------------------------------------------------------------
__global__ __launch_bounds__(256) void slstm_step(
    const float* __restrict__ xw,    // xwbuf + tt*B*4H, [b][4H]
    const float* __restrict__ U,     // [4H][H]
    const float* __restrict__ bU,    // [4H]
    const float* __restrict__ alpha, // [H]
    const float* __restrict__ hin,   // hT layout, 32768 floats
    float* __restrict__ hout,        // hT layout
    float* __restrict__ cst,         // [B][H] in-place
    float* __restrict__ out1t)       // out1c + tt*B*H, [b][H]
{
    __shared__ float4 hs[64 * 32];   // 32 KB: quarter of h
    __shared__ float  zs[16][32];
    const int tid = threadIdx.x;
    const int b = tid & 31, rr = tid >> 5;      // rr 0..7
    const int j0 = blockIdx.x * 4;
    const int g0 = rr >> 2, jj0 = rr & 3;       // local row rr = g0*4+jj0
    const float4* hin4 = (const float4*)hin;
    const float4* U0 = (const float4*)(U + (long)(g0 * HH + j0 + jj0) * HH);
    const float4* U1 = (const float4*)(U + (long)((g0 + 2) * HH + j0 + jj0) * HH);

    float acc0 = 0.f, acc1 = 0.f;
    for (int ph = 0; ph < 4; ++ph) {
        const int base = ph * 2048;
        for (int i = tid; i < 2048; i += 256) hs[i] = hin4[base + i];
        __syncthreads();
#pragma unroll 8
        for (int dd = 0; dd < 64; ++dd) {
            const int d4 = ph * 64 + dd;
            float4 hv = hs[dd * 32 + b];
            float4 u0 = U0[d4];
            float4 u1 = U1[d4];
            acc0 += u0.x * hv.x + u0.y * hv.y + u0.z * hv.z + u0.w * hv.w;
            acc1 += u1.x * hv.x + u1.y * hv.y + u1.z * hv.z + u1.w * hv.w;
        }
        __syncthreads();
    }
    zs[rr][b] = acc0;
    zs[rr + 8][b] = acc1;
    __syncthreads();

    if (tid < 128) {
        const int b2 = tid & 31, jj = tid >> 5;  // jj 0..3
        const int j = j0 + jj;
        const long xb = (long)b2 * FH;
        float zi = xw[xb + j]            + zs[jj][b2]      + bU[j];
        float zf = xw[xb + HH + j]       + zs[4 + jj][b2]  + bU[HH + j];
        float zo = xw[xb + 2 * HH + j]   + zs[8 + jj][b2]  + bU[2 * HH + j];
        float zg = xw[xb + 3 * HH + j]   + zs[12 + jj][b2] + bU[3 * HH + j];
        float ig = 1.f / (1.f + expf(-zi));
        float fg = 1.f / (1.f + expf(-zf));
        float og = 1.f / (1.f + expf(-zo));
        float g  = tanhf(zg);
        float cold = cst[b2 * HH + j];
        float cn = alpha[j] * (fg * cold + ig * g);
        float hn = og * tanhf(cn);
        cst[b2 * HH + j] = cn;
        hout[((long)blockIdx.x * 32 + b2) * 4 + jj] = hn;
        out1t[(long)b2 * HH + j] = hn;
    }
}

// ---------------------------------------------------------------------------
// mLSTM per-step low-rank gate: q[b][r] = xa_t[b][r] * sum_k h[b][k]*Bm[r][k]
// Grid: 512 blocks (32 b x 16 r-groups) x 256 threads (4 waves, 1 dot each).
// ---------------------------------------------------------------------------
__global__ __launch_bounds__(256) void mlstm_q(
    const float* __restrict__ hT, const float* __restrict__ Bm,
    const float* __restrict__ xat, float* __restrict__ q)
{
    const int tid = threadIdx.x;
    const int w = tid >> 6, lane = tid & 63;
    const int b = blockIdx.x >> 4;
    const int r = ((blockIdx.x & 15) << 2) + w;
    const float4* h4 = (const float4*)hT;
    const float4* bm4 = (const float4*)(Bm + (long)r * HH);
    float acc = 0.f;
#pragma unroll
    for (int k = 0; k < 4; ++k) {
        const int d4 = lane + k * 64;
        float4 hv = h4[d4 * 32 + b];
        float4 bv = bm4[d4];
        acc += hv.x * bv.x + hv.y * bv.y + hv.z * bv.z + hv.w * bv.w;
    }
#pragma unroll
    for (int off = 32; off; off >>= 1) acc += __shfl_down(acc, off, 64);
    if (lane == 0) q[b * RR_ + r] = acc * xat[b * RR_ + r];
}

// ---------------------------------------------------------------------------
// mLSTM scan step. Same structure as slstm_step + low-rank mix, fp32 output.
// ---------------------------------------------------------------------------
__global__ __launch_bounds__(256) void mlstm_step(
    const float* __restrict__ xw,
    const float* __restrict__ U,     // Um
    const float* __restrict__ bU,
    const float* __restrict__ P,     // [H][R]
    const float* __restrict__ q,     // [B][R]
    const float* __restrict__ hin,   // hT layout
    float* __restrict__ hout,        // hT layout
    float* __restrict__ cst,
    float* __restrict__ out,         // [B][T][H] fp32 (reference output dtype)
    int t)
{
    __shared__ float4 hs[64 * 32];
    __shared__ float  zs[16][32];
    const int tid = threadIdx.x;
    const int b = tid & 31, rr = tid >> 5;
    const int j0 = blockIdx.x * 4;
    const int g0 = rr >> 2, jj0 = rr & 3;
    const float4* hin4 = (const float4*)hin;
    const float4* U0 = (const float4*)(U + (long)(g0 * HH + j0 + jj0) * HH);
    const float4* U1 = (const float4*)(U + (long)((g0 + 2) * HH + j0 + jj0) * HH);

    float acc0 = 0.f, acc1 = 0.f;
    for (int ph = 0; ph < 4; ++ph) {
        const int base = ph * 2048;
        for (int i = tid; i < 2048; i += 256) hs[i] = hin4[base + i];
        __syncthreads();
#pragma unroll 8
        for (int dd = 0; dd < 64; ++dd) {
            const int d4 = ph * 64 + dd;
            float4 hv = hs[dd * 32 + b];
            float4 u0 = U0[d4];
            float4 u1 = U1[d4];
            acc0 += u0.x * hv.x + u0.y * hv.y + u0.z * hv.z + u0.w * hv.w;
            acc1 += u1.x * hv.x + u1.y * hv.y + u1.z * hv.z + u1.w * hv.w;
        }
        __syncthreads();
    }
    zs[rr][b] = acc0;
    zs[rr + 8][b] = acc1;
    __syncthreads();

    if (tid < 128) {
        const int b2 = tid & 31, jj = tid >> 5;
        const int j = j0 + jj;
        const long xb = (long)b2 * FH;
        float zi = xw[xb + j]          + zs[jj][b2]      + bU[j];
        float zf = xw[xb + HH + j]     + zs[4 + jj][b2]  + bU[HH + j];
        float zo = xw[xb + 2 * HH + j] + zs[8 + jj][b2]  + bU[2 * HH + j];
        float zg = xw[xb + 3 * HH + j] + zs[12 + jj][b2] + bU[3 * HH + j];
        float ig = 1.f / (1.f + expf(-zi));
        float fg = 1.f / (1.f + expf(-zf));
        float og = 1.f / (1.f + expf(-zo));
        float g  = tanhf(zg);
        // low-rank mix: sum_r q[b][r] * P[j][r]
        float mx = 0.f;
        const float4* Pj = (const float4*)(P + (long)j * RR_);
        const float4* qb = (const float4*)(q + (long)b2 * RR_);
#pragma unroll
        for (int r4 = 0; r4 < 16; ++r4) {
            float4 pv = Pj[r4], qv = qb[r4];
            mx += pv.x * qv.x + pv.y * qv.y + pv.z * qv.z + pv.w * qv.w;
        }
        float cold = cst[b2 * HH + j];
        float cn = fg * cold + ig * g + 0.1f * mx;
        float hn = og * tanhf(cn);
        cst[b2 * HH + j] = cn;
        hout[((long)blockIdx.x * 32 + b2) * 4 + jj] = hn;
        out[(long)b2 * (TT_ * HH) + (long)t * HH + j] = hn;   // fp32 store
    }
}

// ---------------------------------------------------------------------------
// Launch: chunked pipeline, ~21 MB fp32 workspace. GEMMs now run on bf16 MFMA
// (fp32->bf16 RNE at staging, fp32 accumulate); scans unchanged fp32.
// ---------------------------------------------------------------------------
extern "C" void kernel_launch(void* const* d_in, const int* in_sizes, int n_in,
                              void* d_out, int out_size, void* d_ws, size_t ws_size,
                              hipStream_t stream) {
    const float* x     = (const float*)d_in[0];
    const float* Ws    = (const float*)d_in[1];
    const float* bWs   = (const float*)d_in[2];
    const float* Us    = (const float*)d_in[3];
    const float* bUs   = (const float*)d_in[4];
    const float* alpha = (const float*)d_in[5];
    const float* Wm    = (const float*)d_in[6];
    const float* bWm   = (const float*)d_in[7];
    const float* Um    = (const float*)d_in[8];
    const float* bUm   = (const float*)d_in[9];
    const float* A     = (const float*)d_in[10];
    const float* Bm    = (const float*)d_in[11];
    const float* P     = (const float*)d_in[12];
    float* out = (float*)d_out;

    float* w      = (float*)d_ws;
    float* xwbuf  = w;                               // TC*B*4H = 4,194,304 f (16 MB)
    float* out1c  = xwbuf + (long)TC * BB * FH;      // TC*B*H  = 1,048,576 f (4 MB)
    float* xac    = out1c + (long)TC * BB * HH;      // TC*B*R  = 65,536 f (256 KB)
    float* hA     = xac + (long)TC * BB * RR_;       // states: 32768 f each
    float* hB     = hA + BB * HH;
    float* cS     = hB + BB * HH;
    float* hmA    = cS + BB * HH;
    float* hmB    = hmA + BB * HH;
    float* cM     = hmB + BB * HH;
    float* q      = cM + BB * HH;                    // 2048 f
    // total: 5,506,048 floats = 21.0 MB

    // zero state buffers (hA..q): 6*32768 + 2048 = 198656 floats = 49664 float4
    init_zero<<<194, 256, 0, stream>>>((float4*)hA, 49664);

    dim3 gbig(FH / 128, (TC * BB) / 64);   // (32, 16) = 512 blocks, 2/CU
    dim3 gxa(RR_ / 64, (TC * BB) / 64);    // (1, 16)

    for (int ch = 0; ch < TT_ / TC; ++ch) {
        const int t0 = ch * TC;

        // ---- sLSTM: xw = x_chunk @ Ws.T + bWs (bf16 MFMA) ----
        gemm_mfma<64, 128><<<gbig, 256, 0, stream>>>(
            x + (long)t0 * DD, (long)DD, (long)TT_ * DD, Ws, bWs,
            xwbuf, TC * BB, FH, DD);
        for (int tt = 0; tt < TC; ++tt) {
            const int t = t0 + tt;
            const float* hin = (t & 1) ? hB : hA;
            float* hout      = (t & 1) ? hA : hB;
            slstm_step<<<256, 256, 0, stream>>>(
                xwbuf + (long)tt * BB * FH, Us, bUs, alpha,
                hin, hout, cS, out1c + (long)tt * BB * HH);
        }

        // ---- mLSTM projections for this chunk (xwbuf reuse: stream-ordered) ----
        gemm_mfma<64, 128><<<gbig, 256, 0, stream>>>(
            out1c, (long)BB * HH, (long)HH, Wm, bWm,
            xwbuf, TC * BB, FH, HH);
        gemm_mfma<64, 64><<<gxa, 256, 0, stream>>>(
            out1c, (long)BB * HH, (long)HH, A, nullptr,
            xac, TC * BB, RR_, HH);

        // ---- mLSTM scan ----
        for (int tt = 0; tt < TC; ++tt) {
            const int t = t0 + tt;
            const float* hin = (t & 1) ? hmB : hmA;
            float* hout      = (t & 1) ? hmA : hmB;
            mlstm_q<<<512, 256, 0, stream>>>(hin, Bm, xac + (long)tt * BB * RR_, q);
            mlstm_step<<<256, 256, 0, stream>>>(
                xwbuf + (long)tt * BB * FH, Um, bUm, P, q,
                hin, hout, cM, out, t);
        }
    }
}